// Round 2
// baseline (477.445 us; speedup 1.0000x reference)
//
#include <hip/hip_runtime.h>
#include <math.h>

#define NB 8
#define NC 64
#define NL 4096
#define NDI 128
#define NN 16

// ---------------- workspace layout (float offsets) ----------------
#define OFF_FEATS 0ull          // 6291456   (dead after K2 -> reused by AC/BC/HINIT)
#define OFF_AC    0ull          // 1048576
#define OFF_BC    1048576ull    // 1048576
#define OFF_HINIT 2097152ull    // 1048576
#define OFF_XF    6291456ull    // 2097152   (dead after K3 -> reused by BMAT/CMAT)
#define OFF_BMAT  6291456ull    // 524288
#define OFF_CMAT  6815744ull    // 524288
#define OFF_X1    8388608ull    // 2097152   (live to the end)
#define OFF_XMRAW 10485760ull   // 4194304   (dead after K5 -> reused by YSCAN)
#define OFF_YSCAN 10485760ull
#define OFF_Z     14680064ull   // 4194304   (dead after K10 -> reused by YC/PART/STATS)
#define OFF_YC    14680064ull   // 2097152
#define OFF_PART  16777216ull   // 16384
#define OFF_STATS 16793600ull   // 1024
#define OFF_XMC   18874368ull   // 4194304
#define OFF_DELTA 23068672ull   // 4194304   (dead after K9 -> reused by YO)
#define OFF_YO    23068672ull   // 2097152
#define OFF_WF    27262976ull   // 55552 f32 weights
#define OFF_NSTAT (OFF_WF + 55552ull)  // 3072
#define WS_NEED_FLOATS (OFF_NSTAT + 3072ull)

// weight sub-offsets inside WF (floats)
#define WF_DW3    0
#define WF_DW5    576
#define WF_DW7    2176
#define WF_B3     5312
#define WF_B5     5376
#define WF_B7     5440
#define WF_FUSE   5504
#define WF_FUSEB  17792
#define WF_C2W    17856
#define WF_C2B    19008
#define WF_XPW    19136
#define WF_DTW    23744
#define WF_DTB    24256
#define WF_A      24384
#define WF_DP     26432
#define WF_ONW    26560
#define WF_ONB    26688
#define WF_OPW    26816
#define WF_CFW    35008
#define WF_CFB    39104
#define WF_INPJ   39168

// ---------------- K0: gather all weights into contiguous f32 block (A = -exp(A_log)) ----------------
struct Cvt { const float* src; float* dst; int n; int op; };
struct CvtArgs { Cvt d[22]; };

__global__ __launch_bounds__(256) void k0_cvt(CvtArgs a){
  Cvt c = a.d[blockIdx.x];
  for (int i = threadIdx.x; i < c.n; i += 256){
    float v = c.src[i];
    c.dst[i] = c.op ? -expf(v) : v;
  }
}

// ---------------- K1: 3 depthwise convs (3/5/7) raw + per-plane stats ----------------
__global__ __launch_bounds__(256) void k1_dw(const float* __restrict__ x, const float* __restrict__ wf,
                                             float* __restrict__ feats, float* __restrict__ nstat){
  const int b = blockIdx.x >> 6, c = blockIdx.x & 63;
  const int tid = threadIdx.x;
  __shared__ float xs[70*72];          // zero-padded (3 each side), row stride 72
  __shared__ float red[4][6];
  for (int i = tid; i < 70*72; i += 256) xs[i] = 0.f;
  __syncthreads();
  const float* xp = x + (size_t)blockIdx.x * NL;
  for (int i = tid; i < NL; i += 256){
    int h = i >> 6, w = i & 63;
    xs[(h+3)*72 + (w+3)] = xp[i];
  }
  float w3r[9], w5r[25], w7r[49];
  #pragma unroll
  for (int i=0;i<9;i++)  w3r[i] = wf[WF_DW3 + c*9 + i];
  #pragma unroll
  for (int i=0;i<25;i++) w5r[i] = wf[WF_DW5 + c*25 + i];
  #pragma unroll
  for (int i=0;i<49;i++) w7r[i] = wf[WF_DW7 + c*49 + i];
  float b3 = wf[WF_B3+c], b5 = wf[WF_B5+c], b7 = wf[WF_B7+c];
  __syncthreads();
  float s3=0,q3=0,s5=0,q5=0,s7=0,q7=0;
  float* f3 = feats + ((size_t)b*192 + c) * NL;
  float* f5 = f3 + (size_t)64*NL;
  float* f7 = f3 + (size_t)128*NL;
  #pragma unroll
  for (int g=0; g<4; g++){
    int p = g*1024 + tid*4;
    int h = p >> 6, w0 = p & 63;
    float a3[4], a5[4], a7[4];
    #pragma unroll
    for (int i=0;i<4;i++){ a3[i]=b3; a5[i]=b5; a7[i]=b7; }
    #pragma unroll
    for (int dy=0; dy<7; dy++){
      float s[10];
      #pragma unroll
      for (int j=0;j<10;j++) s[j] = xs[(h+dy)*72 + w0 + j];
      #pragma unroll
      for (int dx=0;dx<7;dx++){
        float wv = w7r[dy*7+dx];
        #pragma unroll
        for (int i=0;i<4;i++) a7[i] += s[dx+i]*wv;
      }
      if (dy>=1 && dy<=5){
        #pragma unroll
        for (int dx=0;dx<5;dx++){
          float wv = w5r[(dy-1)*5+dx];
          #pragma unroll
          for (int i=0;i<4;i++) a5[i] += s[dx+1+i]*wv;
        }
      }
      if (dy>=2 && dy<=4){
        #pragma unroll
        for (int dx=0;dx<3;dx++){
          float wv = w3r[(dy-2)*3+dx];
          #pragma unroll
          for (int i=0;i<4;i++) a3[i] += s[dx+2+i]*wv;
        }
      }
    }
    *(float4*)(f3+p) = make_float4(a3[0],a3[1],a3[2],a3[3]);
    *(float4*)(f5+p) = make_float4(a5[0],a5[1],a5[2],a5[3]);
    *(float4*)(f7+p) = make_float4(a7[0],a7[1],a7[2],a7[3]);
    #pragma unroll
    for (int i=0;i<4;i++){
      s3+=a3[i]; q3+=a3[i]*a3[i];
      s5+=a5[i]; q5+=a5[i]*a5[i];
      s7+=a7[i]; q7+=a7[i]*a7[i];
    }
  }
  int wid = tid>>6, lane = tid&63;
  float v6[6]={s3,q3,s5,q5,s7,q7};
  #pragma unroll
  for (int j=0;j<6;j++){
    float t = v6[j];
    #pragma unroll
    for (int o=32;o>0;o>>=1) t += __shfl_down(t,o);
    if (!lane) red[wid][j]=t;
  }
  __syncthreads();
  if (tid < 3){
    float su = red[0][tid*2]+red[1][tid*2]+red[2][tid*2]+red[3][tid*2];
    float sq = red[0][tid*2+1]+red[1][tid*2+1]+red[2][tid*2+1]+red[3][tid*2+1];
    float m  = su*(1.f/NL);
    float va = sq*(1.f/NL) - m*m;
    int k = b*192 + tid*64 + c;
    nstat[k*2]   = m;
    nstat[k*2+1] = rsqrtf(va + 1e-5f);
  }
}

// ---------------- K2: fuse 1x1 (192->64), norm+lrelu folded into the load ----------------
__global__ __launch_bounds__(256) void k2_fuse(const float* __restrict__ feats, const float* __restrict__ nstat,
                                               const float* __restrict__ wf, float* __restrict__ xf){
  int t = blockIdx.x;
  int ch = t & 1, pt = (t>>1) & 15, b = t>>5;
  const int l = pt*256 + threadIdx.x;
  float acc[32];
  #pragma unroll
  for (int i=0;i<32;i++) acc[i]=0.f;
  const float* fp = feats + (size_t)b*192*NL + l;
  const float* W  = wf + WF_FUSE + ch*32*192;
  for (int k=0;k<192;k++){
    float m = nstat[(b*192+k)*2], rs = nstat[(b*192+k)*2+1];
    float v = (fp[(size_t)k*NL] - m) * rs;
    v = v > 0.f ? v : 0.01f*v;
    #pragma unroll
    for (int c=0;c<32;c++) acc[c] += W[c*192+k]*v;
  }
  float* xp = xf + (size_t)b*64*NL + (size_t)ch*32*NL + l;
  #pragma unroll
  for (int c=0;c<32;c++) xp[(size_t)c*NL] = acc[c] + wf[WF_FUSEB + ch*32 + c];
}

// ---------------- K3: inorm(xf)+lrelu + x -> x1 ----------------
__global__ __launch_bounds__(256) void k3_norm(const float* __restrict__ xf, const float* __restrict__ x,
                                               float* __restrict__ x1){
  const int tid = threadIdx.x;
  const size_t base = (size_t)blockIdx.x * NL;
  float loc[16]; float s=0.f, q=0.f;
  #pragma unroll
  for (int i=0;i<16;i++){ float v = xf[base + tid + i*256]; loc[i]=v; s+=v; q+=v*v; }
  __shared__ float red[4][2];
  int wid = tid>>6, lane = tid&63;
  #pragma unroll
  for (int o=32;o>0;o>>=1){ s += __shfl_down(s,o); q += __shfl_down(q,o); }
  if (!lane){ red[wid][0]=s; red[wid][1]=q; }
  __syncthreads();
  s = red[0][0]+red[1][0]+red[2][0]+red[3][0];
  q = red[0][1]+red[1][1]+red[2][1]+red[3][1];
  float m = s*(1.f/NL), va = q*(1.f/NL)-m*m, rs = rsqrtf(va+1e-5f);
  #pragma unroll
  for (int i=0;i<16;i++){
    int idx = tid + i*256;
    float v = (loc[i]-m)*rs;
    v = v>0.f ? v : 0.01f*v;
    x1[base+idx] = v + x[base+idx];
  }
}

// ---------------- K4: in_proj (64 -> 256): x in regs, scalar weights ----------------
__global__ __launch_bounds__(256) void k4_inproj(const float* __restrict__ x1, const float* __restrict__ wf,
                                                 float* __restrict__ xmraw, float* __restrict__ z){
  int t = blockIdx.x;
  int jh = t & 1, pt = (t>>1)&15, b = t>>5;
  int l = pt*256 + threadIdx.x;
  float xr[64];
  const float* xp = x1 + (size_t)b*64*NL + l;
  #pragma unroll
  for (int c=0;c<64;c++) xr[c] = xp[(size_t)c*NL];
  const float* W = wf + WF_INPJ + jh*128*64;
  float* dst = (jh==0 ? xmraw : z) + (size_t)b*128*NL + l;
  for (int j=0;j<128;j++){
    float a = 0.f;
    const float* wr = W + j*64;
    #pragma unroll
    for (int c=0;c<64;c++) a += wr[c]*xr[c];
    dst[(size_t)j*NL] = a;
  }
}

// ---------------- K5: depthwise 3x3 + silu ----------------
__global__ __launch_bounds__(256) void k5_dw3(const float* __restrict__ xmraw, const float* __restrict__ wf,
                                              float* __restrict__ xmc){
  const int d = blockIdx.x & 127;
  const int tid = threadIdx.x;
  __shared__ float xs[66*68];
  for (int i=tid;i<66*68;i+=256) xs[i]=0.f;
  __syncthreads();
  const float* xp = xmraw + (size_t)blockIdx.x * NL;
  for (int i=tid;i<NL;i+=256){ int h=i>>6, w=i&63; xs[(h+1)*68 + (w+1)] = xp[i]; }
  float wr[9];
  #pragma unroll
  for (int i=0;i<9;i++) wr[i] = wf[WF_C2W + d*9 + i];
  float bb = wf[WF_C2B + d];
  __syncthreads();
  float* op = xmc + (size_t)blockIdx.x * NL;
  #pragma unroll
  for (int g=0; g<4; g++){
    int p = g*1024 + tid*4;
    int h = p>>6, w0 = p&63;
    float a[4];
    #pragma unroll
    for (int i=0;i<4;i++) a[i]=bb;
    #pragma unroll
    for (int dy=0; dy<3; dy++){
      float s[6];
      #pragma unroll
      for (int j=0;j<6;j++) s[j] = xs[(h+dy)*68 + w0 + j];
      #pragma unroll
      for (int dx=0;dx<3;dx++){
        float wv = wr[dy*3+dx];
        #pragma unroll
        for (int i=0;i<4;i++) a[i] += s[dx+i]*wv;
      }
    }
    float4 o;
    o.x = a[0]/(1.f+__expf(-a[0]));
    o.y = a[1]/(1.f+__expf(-a[1]));
    o.z = a[2]/(1.f+__expf(-a[2]));
    o.w = a[3]/(1.f+__expf(-a[3]));
    *(float4*)(op+p) = o;
  }
}

// ---------------- K6: x_proj (128 -> 36) + dt_proj + double-bias softplus -> delta ----------------
__global__ __launch_bounds__(256) void k6_xproj(const float* __restrict__ xmc, const float* __restrict__ wf,
                                                float* __restrict__ Bm, float* __restrict__ Cm,
                                                float* __restrict__ delta){
  int pt = blockIdx.x & 15, b = blockIdx.x >> 4;
  int l = pt*256 + threadIdx.x;
  float acc[36];
  #pragma unroll
  for (int j=0;j<36;j++) acc[j]=0.f;
  const float* up = xmc + (size_t)b*128*NL + l;
  const float* W  = wf + WF_XPW;
  for (int d=0; d<128; d++){
    float v = up[(size_t)d*NL];
    #pragma unroll
    for (int j=0;j<36;j++) acc[j] += W[j*128+d]*v;
  }
  float* Bp = Bm + (size_t)b*16*NL + l;
  float* Cp = Cm + (size_t)b*16*NL + l;
  #pragma unroll
  for (int n=0;n<16;n++){ Bp[(size_t)n*NL]=acc[4+n]; Cp[(size_t)n*NL]=acc[20+n]; }
  float* dp = delta + (size_t)b*128*NL + l;
  const float* dw = wf + WF_DTW;
  const float* db = wf + WF_DTB;
  for (int d=0; d<128; d++){
    float tt = dw[d*4]*acc[0] + dw[d*4+1]*acc[1] + dw[d*4+2]*acc[2] + dw[d*4+3]*acc[3] + 2.f*db[d];
    float sp = tt > 20.f ? tt : log1pf(__expf(tt));   // softplus (bias applied twice, faithful)
    dp[(size_t)d*NL] = sp;
  }
}

// ---------------- K7: scan pass1 — per-chunk (prodA, composed B) ----------------
__global__ __launch_bounds__(128) void k7_scan1(const float* __restrict__ delta, const float* __restrict__ u,
                                                const float* __restrict__ Bm, const float* __restrict__ wf,
                                                float* __restrict__ Ac, float* __restrict__ Bc){
  int k = blockIdx.x & 63, b = blockIdx.x >> 6;
  int d = threadIdx.x;
  int l0 = k*64;
  float A[16], P[16], Q[16];
  const float* Af = wf + WF_A + d*16;
  #pragma unroll
  for (int n=0;n<16;n++){ A[n]=Af[n]; P[n]=1.f; Q[n]=0.f; }
  const float4* dp = (const float4*)(delta + ((size_t)b*128+d)*NL + l0);
  const float4* up = (const float4*)(u     + ((size_t)b*128+d)*NL + l0);
  const float* Bp  = Bm + (size_t)b*16*NL + l0;
  for (int li4=0; li4<16; li4++){
    float4 d4 = dp[li4], u4 = up[li4];
    float des[4]={d4.x,d4.y,d4.z,d4.w}, uss[4]={u4.x,u4.y,u4.z,u4.w};
    #pragma unroll
    for (int s=0;s<4;s++){
      int li = li4*4+s;
      float de = des[s];
      float du = de*uss[s];
      #pragma unroll
      for (int n=0;n<16;n++){
        float a = __expf(de*A[n]);
        P[n] *= a;
        Q[n] = a*Q[n] + du*Bp[(size_t)n*NL + li];
      }
    }
  }
  size_t base = (((size_t)k*NB + b)*128 + d)*16;
  #pragma unroll
  for (int n=0;n<16;n++){ Ac[base+n]=P[n]; Bc[base+n]=Q[n]; }
}

// ---------------- K8: middle scan over chunk aggregates ----------------
__global__ __launch_bounds__(256) void k8_mid(const float* __restrict__ Ac, const float* __restrict__ Bc,
                                              float* __restrict__ Hi){
  int idx = blockIdx.x*256 + threadIdx.x;   // (b*128+d)*16+n, 16384 total
  float h = 0.f;
  for (int k=0;k<64;k++){
    size_t o = (size_t)k*16384 + idx;
    Hi[o] = h;
    h = Ac[o]*h + Bc[o];
  }
}

// ---------------- K9: scan pass2 — reconstruct h, emit y = sum_n h*C + u*Dp ----------------
__global__ __launch_bounds__(128) void k9_scan2(const float* __restrict__ delta, const float* __restrict__ u,
                                                const float* __restrict__ Bm, const float* __restrict__ Cm,
                                                const float* __restrict__ wf, const float* __restrict__ Hi,
                                                float* __restrict__ y){
  int k = blockIdx.x & 63, b = blockIdx.x >> 6;
  int d = threadIdx.x;
  int l0 = k*64;
  float A[16], h[16];
  const float* Af = wf + WF_A + d*16;
  size_t hb = (((size_t)k*NB + b)*128 + d)*16;
  #pragma unroll
  for (int n=0;n<16;n++){ A[n]=Af[n]; h[n]=Hi[hb+n]; }
  float Dv = wf[WF_DP + d];
  const float4* dp = (const float4*)(delta + ((size_t)b*128+d)*NL + l0);
  const float4* up = (const float4*)(u     + ((size_t)b*128+d)*NL + l0);
  const float* Bp  = Bm + (size_t)b*16*NL + l0;
  const float* Cp  = Cm + (size_t)b*16*NL + l0;
  float4* yp = (float4*)(y + ((size_t)b*128+d)*NL + l0);
  for (int li4=0; li4<16; li4++){
    float4 d4 = dp[li4], u4 = up[li4];
    float des[4]={d4.x,d4.y,d4.z,d4.w}, uss[4]={u4.x,u4.y,u4.z,u4.w};
    float out[4];
    #pragma unroll
    for (int s=0;s<4;s++){
      int li = li4*4+s;
      float de = des[s], uu = uss[s];
      float du = de*uu;
      float yv = uu*Dv;
      #pragma unroll
      for (int n=0;n<16;n++){
        float a = __expf(de*A[n]);
        h[n] = a*h[n] + du*Bp[(size_t)n*NL+li];
        yv += h[n]*Cp[(size_t)n*NL+li];
      }
      out[s]=yv;
    }
    yp[li4] = make_float4(out[0],out[1],out[2],out[3]);
  }
}

// ---------------- K10: LayerNorm(d) * silu(z) then out_proj (128 -> 64) ----------------
__global__ __launch_bounds__(256) void k10_out(const float* __restrict__ y, const float* __restrict__ z,
                                               const float* __restrict__ wf, float* __restrict__ yo){
  int t = blockIdx.x;
  int ch = t & 1, pt = (t>>1)&15, b = t>>5;
  int l = pt*256 + threadIdx.x;
  const float* yp = y + (size_t)b*128*NL + l;
  float s=0.f, q=0.f;
  for (int dd=0;dd<128;dd++){ float v = yp[(size_t)dd*NL]; s+=v; q+=v*v; }
  float m = s*(1.f/128.f), va = q*(1.f/128.f)-m*m, rs = rsqrtf(va+1e-5f);
  const float* zp = z + (size_t)b*128*NL + l;
  const float* W  = wf + WF_OPW + ch*32*128;
  float acc[32];
  #pragma unroll
  for (int c=0;c<32;c++) acc[c]=0.f;
  for (int dd=0;dd<128;dd++){
    float v  = yp[(size_t)dd*NL];
    float tt = (v-m)*rs*wf[WF_ONW+dd] + wf[WF_ONB+dd];
    float zv = zp[(size_t)dd*NL];
    tt *= zv/(1.f+__expf(-zv));
    #pragma unroll
    for (int c=0;c<32;c++) acc[c] += W[c*128+dd]*tt;
  }
  float* op = yo + (size_t)b*64*NL + (size_t)ch*32*NL + l;
  #pragma unroll
  for (int c=0;c<32;c++) op[(size_t)c*NL] = acc[c];
}

// ---------------- K11a: cf 1x1 conv (64 -> 64) + per-(b,c) partial stats ----------------
__global__ __launch_bounds__(256) void k11a_cf(const float* __restrict__ yo, const float* __restrict__ wf,
                                               float* __restrict__ yc, float* __restrict__ part){
  int t = blockIdx.x;
  int ch = t & 1, pt = (t>>1)&15, b = t>>5;
  int l = pt*256 + threadIdx.x;
  const float* yp = yo + (size_t)b*64*NL + l;
  const float* W  = wf + WF_CFW + ch*32*64;
  float acc[32];
  #pragma unroll
  for (int c=0;c<32;c++) acc[c] = wf[WF_CFB + ch*32 + c];
  for (int kk=0;kk<64;kk++){
    float v = yp[(size_t)kk*NL];
    #pragma unroll
    for (int c=0;c<32;c++) acc[c] += W[c*64+kk]*v;
  }
  float* op = yc + (size_t)b*64*NL + (size_t)ch*32*NL + l;
  #pragma unroll
  for (int c=0;c<32;c++) op[(size_t)c*NL] = acc[c];
  __shared__ float redS[32][4], redQ[32][4];
  int wid = threadIdx.x>>6, lane = threadIdx.x&63;
  #pragma unroll
  for (int c=0;c<32;c++){
    float sv = acc[c], qv = acc[c]*acc[c];
    #pragma unroll
    for (int o=32;o>0;o>>=1){ sv += __shfl_down(sv,o); qv += __shfl_down(qv,o); }
    if (!lane){ redS[c][wid]=sv; redQ[c][wid]=qv; }
  }
  __syncthreads();
  if (threadIdx.x < 32){
    int c = threadIdx.x;
    float sv = redS[c][0]+redS[c][1]+redS[c][2]+redS[c][3];
    float qv = redQ[c][0]+redQ[c][1]+redQ[c][2]+redQ[c][3];
    int cc = ch*32 + c;
    size_t pidx = (((size_t)b*64 + cc)*16 + pt)*2;
    part[pidx] = sv; part[pidx+1] = qv;
  }
}

// ---------------- K11b: finalize per-(b,c) mean/rsqrt ----------------
__global__ __launch_bounds__(256) void k11b_stats(const float* __restrict__ part, float* __restrict__ stats){
  int i = blockIdx.x*256 + threadIdx.x;
  if (i >= 512) return;
  float s=0.f, q=0.f;
  #pragma unroll
  for (int t2=0;t2<16;t2++){ s += part[((size_t)i*16+t2)*2]; q += part[((size_t)i*16+t2)*2+1]; }
  float m = s*(1.f/NL), va = q*(1.f/NL) - m*m;
  stats[i*2] = m; stats[i*2+1] = rsqrtf(va+1e-5f);
}

// ---------------- K11c: out = x1 + inorm(yc), write f32 ----------------
__global__ __launch_bounds__(256) void k11c_final(const float* __restrict__ yc, const float* __restrict__ stats,
                                                  const float* __restrict__ x1, float* __restrict__ out){
  int bc = blockIdx.x;
  float m = stats[bc*2], rs = stats[bc*2+1];
  size_t base = (size_t)bc*NL;
  for (int i=threadIdx.x;i<NL;i+=256){
    float v = (yc[base+i]-m)*rs;
    out[base+i] = x1[base+i] + v;
  }
}

// ---------------- host ----------------
extern "C" void kernel_launch(void* const* d_in, const int* in_sizes, int n_in,
                              void* d_out, int out_size, void* d_ws, size_t ws_size,
                              hipStream_t stream) {
  if (ws_size < WS_NEED_FLOATS * sizeof(float)) return;  // insufficient scratch; bail cleanly
  const float* x     = (const float*)d_in[0];
  const float* dw3w  = (const float*)d_in[1];
  const float* dw3b  = (const float*)d_in[2];
  const float* dw5w  = (const float*)d_in[3];
  const float* dw5b  = (const float*)d_in[4];
  const float* dw7w  = (const float*)d_in[5];
  const float* dw7b  = (const float*)d_in[6];
  const float* fusew = (const float*)d_in[7];
  const float* fuseb = (const float*)d_in[8];
  const float* inpjw = (const float*)d_in[9];
  const float* c2w   = (const float*)d_in[10];
  const float* c2b   = (const float*)d_in[11];
  const float* xpw   = (const float*)d_in[12];
  const float* dtw   = (const float*)d_in[13];
  const float* dtb   = (const float*)d_in[14];
  const float* alog  = (const float*)d_in[15];
  const float* dpv   = (const float*)d_in[16];
  const float* onw   = (const float*)d_in[17];
  const float* onb   = (const float*)d_in[18];
  const float* opw   = (const float*)d_in[19];
  const float* cfw   = (const float*)d_in[20];
  const float* cfb   = (const float*)d_in[21];

  float* ws    = (float*)d_ws;
  float* wf    = ws + OFF_WF;
  float* feats = ws + OFF_FEATS;
  float* nstat = ws + OFF_NSTAT;
  float* xf    = ws + OFF_XF;
  float* x1    = ws + OFF_X1;
  float* xmraw = ws + OFF_XMRAW;
  float* z     = ws + OFF_Z;
  float* xmc   = ws + OFF_XMC;
  float* Bmw   = ws + OFF_BMAT;
  float* Cmw   = ws + OFF_CMAT;
  float* delta = ws + OFF_DELTA;
  float* Acb   = ws + OFF_AC;
  float* Bcb   = ws + OFF_BC;
  float* Hi    = ws + OFF_HINIT;
  float* yscan = ws + OFF_YSCAN;
  float* yo    = ws + OFF_YO;
  float* yc    = ws + OFF_YC;
  float* part  = ws + OFF_PART;
  float* stats = ws + OFF_STATS;

  CvtArgs ca; int ns = 0;
  auto add = [&](const float* s, int off, int n, int op){
    ca.d[ns].src = s; ca.d[ns].dst = wf + off; ca.d[ns].n = n; ca.d[ns].op = op; ns++;
  };
  add(dw3w, WF_DW3, 576, 0);   add(dw5w, WF_DW5, 1600, 0);  add(dw7w, WF_DW7, 3136, 0);
  add(dw3b, WF_B3, 64, 0);     add(dw5b, WF_B5, 64, 0);     add(dw7b, WF_B7, 64, 0);
  add(fusew, WF_FUSE, 12288, 0); add(fuseb, WF_FUSEB, 64, 0);
  add(c2w, WF_C2W, 1152, 0);   add(c2b, WF_C2B, 128, 0);
  add(xpw, WF_XPW, 4608, 0);   add(dtw, WF_DTW, 512, 0);    add(dtb, WF_DTB, 128, 0);
  add(alog, WF_A, 2048, 1);    // A = -exp(A_log)
  add(dpv, WF_DP, 128, 0);
  add(onw, WF_ONW, 128, 0);    add(onb, WF_ONB, 128, 0);
  add(opw, WF_OPW, 8192, 0);
  add(cfw, WF_CFW, 4096, 0);   add(cfb, WF_CFB, 64, 0);
  add(inpjw, WF_INPJ, 16384, 0);

  k0_cvt<<<ns, 256, 0, stream>>>(ca);
  k1_dw<<<512, 256, 0, stream>>>(x, wf, feats, nstat);
  k2_fuse<<<256, 256, 0, stream>>>(feats, nstat, wf, xf);
  k3_norm<<<512, 256, 0, stream>>>(xf, x, x1);
  k4_inproj<<<256, 256, 0, stream>>>(x1, wf, xmraw, z);
  k5_dw3<<<1024, 256, 0, stream>>>(xmraw, wf, xmc);
  k6_xproj<<<128, 256, 0, stream>>>(xmc, wf, Bmw, Cmw, delta);
  k7_scan1<<<512, 128, 0, stream>>>(delta, xmc, Bmw, wf, Acb, Bcb);
  k8_mid<<<64, 256, 0, stream>>>(Acb, Bcb, Hi);
  k9_scan2<<<512, 128, 0, stream>>>(delta, xmc, Bmw, Cmw, wf, Hi, yscan);
  k10_out<<<256, 256, 0, stream>>>(yscan, z, wf, yo);
  k11a_cf<<<256, 256, 0, stream>>>(yo, wf, yc, part);
  k11b_stats<<<2, 256, 0, stream>>>(part, stats);
  k11c_final<<<512, 256, 0, stream>>>(yc, stats, x1, (float*)d_out);
}

// Round 3
// 348.911 us; speedup vs baseline: 1.3684x; 1.3684x over previous
//
#include <hip/hip_runtime.h>
#include <math.h>

#define NB 8
#define NC 64
#define NL 4096
#define NDI 128
#define NN 16
#define CHUNK 32
#define NKCH 128   // NL / CHUNK

// ---------------- workspace layout (float offsets) ----------------
#define OFF_FEATS 0ull          // 6291456 (dead after K2 -> reused by AC/BC/HINIT)
#define OFF_AC    0ull          // 2097152
#define OFF_BC    2097152ull    // 2097152
#define OFF_HINIT 4194304ull    // 2097152
#define OFF_XF    6291456ull    // 2097152 (dead after K3 -> reused by BMAT/CMAT)
#define OFF_BMAT  6291456ull    // 524288
#define OFF_CMAT  6815744ull    // 524288
#define OFF_X1    8388608ull    // 2097152 (live to the end)
#define OFF_XMRAW 10485760ull   // 4194304 (dead after K5 -> reused by YSCAN)
#define OFF_YSCAN 10485760ull
#define OFF_Z     14680064ull   // 4194304 (dead after gate -> reused by YC/PART/STATS)
#define OFF_YC    14680064ull   // 2097152
#define OFF_PART  16777216ull   // 16384
#define OFF_STATS 16793600ull   // 1024
#define OFF_XMC   18874368ull   // 4194304
#define OFF_DELTA 23068672ull   // 4194304 (dead after K9 -> reused by G)
#define OFF_G     23068672ull   // 4194304
#define OFF_WF    27262976ull   // 55552 f32 weights
#define OFF_NSTAT (OFF_WF + 55552ull)   // 3072
#define OFF_WCOMB (OFF_WF + 58624ull)   // 8192 (cf_w @ op_w)
#define WS_NEED_FLOATS (OFF_WF + 66816ull)

// weight sub-offsets inside WF (floats)
#define WF_DW3    0
#define WF_DW5    576
#define WF_DW7    2176
#define WF_B3     5312
#define WF_B5     5376
#define WF_B7     5440
#define WF_FUSE   5504
#define WF_FUSEB  17792
#define WF_C2W    17856
#define WF_C2B    19008
#define WF_XPW    19136
#define WF_DTW    23744
#define WF_DTB    24256
#define WF_A      24384
#define WF_DP     26432
#define WF_ONW    26560
#define WF_ONB    26688
#define WF_OPW    26816
#define WF_CFW    35008
#define WF_CFB    39104
#define WF_INPJ   39168

// ---------------- K0: gather all weights into contiguous f32 block (A = -exp(A_log)) ----------------
struct Cvt { const float* src; float* dst; int n; int op; };
struct CvtArgs { Cvt d[22]; };

__global__ __launch_bounds__(256) void k0_cvt(CvtArgs a){
  Cvt c = a.d[blockIdx.x];
  for (int i = threadIdx.x; i < c.n; i += 256){
    float v = c.src[i];
    c.dst[i] = c.op ? -expf(v) : v;
  }
}

// ---------------- K0b: W_comb = cf_w(64x64) @ op_w(64x128) ----------------
__global__ __launch_bounds__(256) void k0b_comb(const float* __restrict__ cfw, const float* __restrict__ opw,
                                                float* __restrict__ wcomb){
  int idx = blockIdx.x*256 + threadIdx.x;   // 8192 outputs
  int c = idx >> 7, kk = idx & 127;
  float s = 0.f;
  #pragma unroll
  for (int j=0;j<64;j++) s += cfw[c*64+j] * opw[j*128+kk];
  wcomb[idx] = s;
}

// ---------------- K1: 3 depthwise convs (3/5/7) raw + per-plane stats ----------------
__global__ __launch_bounds__(256) void k1_dw(const float* __restrict__ x, const float* __restrict__ wf,
                                             float* __restrict__ feats, float* __restrict__ nstat){
  const int b = blockIdx.x >> 6, c = blockIdx.x & 63;
  const int tid = threadIdx.x;
  __shared__ float xs[70*72];          // zero-padded (3 each side), row stride 72
  __shared__ float red[4][6];
  for (int i = tid; i < 70*72; i += 256) xs[i] = 0.f;
  __syncthreads();
  const float* xp = x + (size_t)blockIdx.x * NL;
  for (int i = tid; i < NL; i += 256){
    int h = i >> 6, w = i & 63;
    xs[(h+3)*72 + (w+3)] = xp[i];
  }
  float w3r[9], w5r[25], w7r[49];
  #pragma unroll
  for (int i=0;i<9;i++)  w3r[i] = wf[WF_DW3 + c*9 + i];
  #pragma unroll
  for (int i=0;i<25;i++) w5r[i] = wf[WF_DW5 + c*25 + i];
  #pragma unroll
  for (int i=0;i<49;i++) w7r[i] = wf[WF_DW7 + c*49 + i];
  float b3 = wf[WF_B3+c], b5 = wf[WF_B5+c], b7 = wf[WF_B7+c];
  __syncthreads();
  float s3=0,q3=0,s5=0,q5=0,s7=0,q7=0;
  float* f3 = feats + ((size_t)b*192 + c) * NL;
  float* f5 = f3 + (size_t)64*NL;
  float* f7 = f3 + (size_t)128*NL;
  #pragma unroll
  for (int g=0; g<4; g++){
    int p = g*1024 + tid*4;
    int h = p >> 6, w0 = p & 63;
    float a3[4], a5[4], a7[4];
    #pragma unroll
    for (int i=0;i<4;i++){ a3[i]=b3; a5[i]=b5; a7[i]=b7; }
    #pragma unroll
    for (int dy=0; dy<7; dy++){
      float s[10];
      #pragma unroll
      for (int j=0;j<10;j++) s[j] = xs[(h+dy)*72 + w0 + j];
      #pragma unroll
      for (int dx=0;dx<7;dx++){
        float wv = w7r[dy*7+dx];
        #pragma unroll
        for (int i=0;i<4;i++) a7[i] += s[dx+i]*wv;
      }
      if (dy>=1 && dy<=5){
        #pragma unroll
        for (int dx=0;dx<5;dx++){
          float wv = w5r[(dy-1)*5+dx];
          #pragma unroll
          for (int i=0;i<4;i++) a5[i] += s[dx+1+i]*wv;
        }
      }
      if (dy>=2 && dy<=4){
        #pragma unroll
        for (int dx=0;dx<3;dx++){
          float wv = w3r[(dy-2)*3+dx];
          #pragma unroll
          for (int i=0;i<4;i++) a3[i] += s[dx+2+i]*wv;
        }
      }
    }
    *(float4*)(f3+p) = make_float4(a3[0],a3[1],a3[2],a3[3]);
    *(float4*)(f5+p) = make_float4(a5[0],a5[1],a5[2],a5[3]);
    *(float4*)(f7+p) = make_float4(a7[0],a7[1],a7[2],a7[3]);
    #pragma unroll
    for (int i=0;i<4;i++){
      s3+=a3[i]; q3+=a3[i]*a3[i];
      s5+=a5[i]; q5+=a5[i]*a5[i];
      s7+=a7[i]; q7+=a7[i]*a7[i];
    }
  }
  int wid = tid>>6, lane = tid&63;
  float v6[6]={s3,q3,s5,q5,s7,q7};
  #pragma unroll
  for (int j=0;j<6;j++){
    float t = v6[j];
    #pragma unroll
    for (int o=32;o>0;o>>=1) t += __shfl_down(t,o);
    if (!lane) red[wid][j]=t;
  }
  __syncthreads();
  if (tid < 3){
    float su = red[0][tid*2]+red[1][tid*2]+red[2][tid*2]+red[3][tid*2];
    float sq = red[0][tid*2+1]+red[1][tid*2+1]+red[2][tid*2+1]+red[3][tid*2+1];
    float m  = su*(1.f/NL);
    float va = sq*(1.f/NL) - m*m;
    int k = b*192 + tid*64 + c;
    nstat[k*2]   = m;
    nstat[k*2+1] = rsqrtf(va + 1e-5f);
  }
}

// ---------------- K2: fuse 1x1 (192->64), 4 groups x 16ch; bid = g*128 + tile ----------------
__global__ __launch_bounds__(256) void k2_fuse(const float* __restrict__ feats, const float* __restrict__ nstat,
                                               const float* __restrict__ wf, float* __restrict__ xf){
  int g = blockIdx.x >> 7, tile = blockIdx.x & 127;
  int b = tile >> 4, pt = tile & 15;
  const int l = pt*256 + threadIdx.x;
  float acc[16];
  #pragma unroll
  for (int i=0;i<16;i++) acc[i]=0.f;
  const float* fp = feats + (size_t)b*192*NL + l;
  const float* W  = wf + WF_FUSE + g*16*192;
  for (int k=0;k<192;k++){
    float m = nstat[(b*192+k)*2], rs = nstat[(b*192+k)*2+1];
    float v = (fp[(size_t)k*NL] - m) * rs;
    v = v > 0.f ? v : 0.01f*v;
    #pragma unroll
    for (int c=0;c<16;c++) acc[c] += W[c*192+k]*v;
  }
  float* xp = xf + (size_t)b*64*NL + (size_t)g*16*NL + l;
  #pragma unroll
  for (int c=0;c<16;c++) xp[(size_t)c*NL] = acc[c] + wf[WF_FUSEB + g*16 + c];
}

// ---------------- K3: inorm(xf)+lrelu + x -> x1 ----------------
__global__ __launch_bounds__(256) void k3_norm(const float* __restrict__ xf, const float* __restrict__ x,
                                               float* __restrict__ x1){
  const int tid = threadIdx.x;
  const size_t base = (size_t)blockIdx.x * NL;
  float loc[16]; float s=0.f, q=0.f;
  #pragma unroll
  for (int i=0;i<16;i++){ float v = xf[base + tid + i*256]; loc[i]=v; s+=v; q+=v*v; }
  __shared__ float red[4][2];
  int wid = tid>>6, lane = tid&63;
  #pragma unroll
  for (int o=32;o>0;o>>=1){ s += __shfl_down(s,o); q += __shfl_down(q,o); }
  if (!lane){ red[wid][0]=s; red[wid][1]=q; }
  __syncthreads();
  s = red[0][0]+red[1][0]+red[2][0]+red[3][0];
  q = red[0][1]+red[1][1]+red[2][1]+red[3][1];
  float m = s*(1.f/NL), va = q*(1.f/NL)-m*m, rs = rsqrtf(va+1e-5f);
  #pragma unroll
  for (int i=0;i<16;i++){
    int idx = tid + i*256;
    float v = (loc[i]-m)*rs;
    v = v>0.f ? v : 0.01f*v;
    x1[base+idx] = v + x[base+idx];
  }
}

// ---------------- K4: in_proj (64 -> 256): 8 groups x 32ch; bid = jg*128 + tile ----------------
__global__ __launch_bounds__(256) void k4_inproj(const float* __restrict__ x1, const float* __restrict__ wf,
                                                 float* __restrict__ xmraw, float* __restrict__ z){
  int jg = blockIdx.x >> 7, tile = blockIdx.x & 127;
  int b = tile >> 4, pt = tile & 15;
  int l = pt*256 + threadIdx.x;
  float acc[32];
  #pragma unroll
  for (int i=0;i<32;i++) acc[i]=0.f;
  const float* xp = x1 + (size_t)b*64*NL + l;
  const float* W = wf + WF_INPJ + jg*32*64;
  for (int c=0;c<64;c++){
    float v = xp[(size_t)c*NL];
    #pragma unroll
    for (int j=0;j<32;j++) acc[j] += W[j*64+c]*v;
  }
  int j0 = jg*32;
  float* dst = (j0 < 128 ? xmraw + (size_t)b*128*NL + (size_t)j0*NL
                         : z     + (size_t)b*128*NL + (size_t)(j0-128)*NL) + l;
  #pragma unroll
  for (int j=0;j<32;j++) dst[(size_t)j*NL] = acc[j];
}

// ---------------- K5: depthwise 3x3 + silu ----------------
__global__ __launch_bounds__(256) void k5_dw3(const float* __restrict__ xmraw, const float* __restrict__ wf,
                                              float* __restrict__ xmc){
  const int d = blockIdx.x & 127;
  const int tid = threadIdx.x;
  __shared__ float xs[66*68];
  for (int i=tid;i<66*68;i+=256) xs[i]=0.f;
  __syncthreads();
  const float* xp = xmraw + (size_t)blockIdx.x * NL;
  for (int i=tid;i<NL;i+=256){ int h=i>>6, w=i&63; xs[(h+1)*68 + (w+1)] = xp[i]; }
  float wr[9];
  #pragma unroll
  for (int i=0;i<9;i++) wr[i] = wf[WF_C2W + d*9 + i];
  float bb = wf[WF_C2B + d];
  __syncthreads();
  float* op = xmc + (size_t)blockIdx.x * NL;
  #pragma unroll
  for (int g=0; g<4; g++){
    int p = g*1024 + tid*4;
    int h = p>>6, w0 = p&63;
    float a[4];
    #pragma unroll
    for (int i=0;i<4;i++) a[i]=bb;
    #pragma unroll
    for (int dy=0; dy<3; dy++){
      float s[6];
      #pragma unroll
      for (int j=0;j<6;j++) s[j] = xs[(h+dy)*68 + w0 + j];
      #pragma unroll
      for (int dx=0;dx<3;dx++){
        float wv = wr[dy*3+dx];
        #pragma unroll
        for (int i=0;i<4;i++) a[i] += s[dx+i]*wv;
      }
    }
    float4 o;
    o.x = a[0]/(1.f+__expf(-a[0]));
    o.y = a[1]/(1.f+__expf(-a[1]));
    o.z = a[2]/(1.f+__expf(-a[2]));
    o.w = a[3]/(1.f+__expf(-a[3]));
    *(float4*)(op+p) = o;
  }
}

// ---------------- K6: x_proj split into 3 groups: g0=B(16), g1=C(16), g2=dt+delta ----------------
__global__ __launch_bounds__(256) void k6_xproj(const float* __restrict__ xmc, const float* __restrict__ wf,
                                                float* __restrict__ Bm, float* __restrict__ Cm,
                                                float* __restrict__ delta){
  int g = blockIdx.x >> 7, tile = blockIdx.x & 127;
  int b = tile >> 4, pt = tile & 15;
  int l = pt*256 + threadIdx.x;
  const float* up = xmc + (size_t)b*128*NL + l;
  if (g < 2){
    float acc[16];
    #pragma unroll
    for (int j=0;j<16;j++) acc[j]=0.f;
    const float* W = wf + WF_XPW + (4 + g*16)*128;
    for (int d=0; d<128; d++){
      float v = up[(size_t)d*NL];
      #pragma unroll
      for (int j=0;j<16;j++) acc[j] += W[j*128+d]*v;
    }
    float* P = (g==0 ? Bm : Cm) + (size_t)b*16*NL + l;
    #pragma unroll
    for (int n=0;n<16;n++) P[(size_t)n*NL]=acc[n];
  } else {
    float acc[4];
    #pragma unroll
    for (int j=0;j<4;j++) acc[j]=0.f;
    const float* W = wf + WF_XPW;
    for (int d=0; d<128; d++){
      float v = up[(size_t)d*NL];
      #pragma unroll
      for (int j=0;j<4;j++) acc[j] += W[j*128+d]*v;
    }
    float* dp = delta + (size_t)b*128*NL + l;
    const float* dw = wf + WF_DTW;
    const float* db = wf + WF_DTB;
    for (int d=0; d<128; d++){
      float tt = dw[d*4]*acc[0] + dw[d*4+1]*acc[1] + dw[d*4+2]*acc[2] + dw[d*4+3]*acc[3] + 2.f*db[d];
      float sp = tt > 20.f ? tt : log1pf(__expf(tt));   // softplus (bias applied twice, faithful)
      dp[(size_t)d*NL] = sp;
    }
  }
}

// ---------------- K7: scan pass1 — per-chunk (prodA, composed B), CHUNK=32 ----------------
__global__ __launch_bounds__(128) void k7_scan1(const float* __restrict__ delta, const float* __restrict__ u,
                                                const float* __restrict__ Bm, const float* __restrict__ wf,
                                                float* __restrict__ Ac, float* __restrict__ Bc){
  int k = blockIdx.x & (NKCH-1), b = blockIdx.x >> 7;
  int d = threadIdx.x;
  int l0 = k*CHUNK;
  __shared__ float Bs[16*CHUNK];
  for (int i = d; i < 16*CHUNK; i += 128){
    int n = i >> 5, li = i & 31;
    Bs[i] = Bm[(size_t)b*16*NL + (size_t)n*NL + l0 + li];
  }
  float A[16], P[16], Q[16];
  const float* Af = wf + WF_A + d*16;
  #pragma unroll
  for (int n=0;n<16;n++){ A[n]=Af[n]; P[n]=1.f; Q[n]=0.f; }
  const float4* dp = (const float4*)(delta + ((size_t)b*128+d)*NL + l0);
  const float4* up = (const float4*)(u     + ((size_t)b*128+d)*NL + l0);
  __syncthreads();
  for (int li4=0; li4<CHUNK/4; li4++){
    float4 d4 = dp[li4], u4 = up[li4];
    float des[4]={d4.x,d4.y,d4.z,d4.w}, uss[4]={u4.x,u4.y,u4.z,u4.w};
    #pragma unroll
    for (int s=0;s<4;s++){
      int li = li4*4+s;
      float de = des[s];
      float du = de*uss[s];
      #pragma unroll
      for (int n=0;n<16;n++){
        float a = __expf(de*A[n]);
        P[n] *= a;
        Q[n] = a*Q[n] + du*Bs[n*CHUNK + li];
      }
    }
  }
  size_t base = (((size_t)k*NB + b)*128 + d)*16;
  #pragma unroll
  for (int n=0;n<16;n++){ Ac[base+n]=P[n]; Bc[base+n]=Q[n]; }
}

// ---------------- K8: middle scan over chunk aggregates ----------------
__global__ __launch_bounds__(256) void k8_mid(const float* __restrict__ Ac, const float* __restrict__ Bc,
                                              float* __restrict__ Hi){
  int idx = blockIdx.x*256 + threadIdx.x;   // (b*128+d)*16+n, 16384 total
  float h = 0.f;
  for (int k=0;k<NKCH;k++){
    size_t o = (size_t)k*16384 + idx;
    Hi[o] = h;
    h = Ac[o]*h + Bc[o];
  }
}

// ---------------- K9: scan pass2 — reconstruct h, emit y = sum_n h*C + u*Dp ----------------
__global__ __launch_bounds__(128) void k9_scan2(const float* __restrict__ delta, const float* __restrict__ u,
                                                const float* __restrict__ Bm, const float* __restrict__ Cm,
                                                const float* __restrict__ wf, const float* __restrict__ Hi,
                                                float* __restrict__ y){
  int k = blockIdx.x & (NKCH-1), b = blockIdx.x >> 7;
  int d = threadIdx.x;
  int l0 = k*CHUNK;
  __shared__ float Bs[16*CHUNK], Cs[16*CHUNK];
  for (int i = d; i < 16*CHUNK; i += 128){
    int n = i >> 5, li = i & 31;
    Bs[i] = Bm[(size_t)b*16*NL + (size_t)n*NL + l0 + li];
    Cs[i] = Cm[(size_t)b*16*NL + (size_t)n*NL + l0 + li];
  }
  float A[16], h[16];
  const float* Af = wf + WF_A + d*16;
  size_t hb = (((size_t)k*NB + b)*128 + d)*16;
  #pragma unroll
  for (int n=0;n<16;n++){ A[n]=Af[n]; h[n]=Hi[hb+n]; }
  float Dv = wf[WF_DP + d];
  const float4* dp = (const float4*)(delta + ((size_t)b*128+d)*NL + l0);
  const float4* up = (const float4*)(u     + ((size_t)b*128+d)*NL + l0);
  float4* yp = (float4*)(y + ((size_t)b*128+d)*NL + l0);
  __syncthreads();
  for (int li4=0; li4<CHUNK/4; li4++){
    float4 d4 = dp[li4], u4 = up[li4];
    float des[4]={d4.x,d4.y,d4.z,d4.w}, uss[4]={u4.x,u4.y,u4.z,u4.w};
    float out[4];
    #pragma unroll
    for (int s=0;s<4;s++){
      int li = li4*4+s;
      float de = des[s], uu = uss[s];
      float du = de*uu;
      float yv = uu*Dv;
      #pragma unroll
      for (int n=0;n<16;n++){
        float a = __expf(de*A[n]);
        h[n] = a*h[n] + du*Bs[n*CHUNK+li];
        yv += h[n]*Cs[n*CHUNK+li];
      }
      out[s]=yv;
    }
    yp[li4] = make_float4(out[0],out[1],out[2],out[3]);
  }
}

// ---------------- K10g: G = (LN(y)*w+b) * silu(z); 128px x 2 ch-halves per block ----------------
__global__ __launch_bounds__(256) void k10g(const float* __restrict__ y, const float* __restrict__ z,
                                            const float* __restrict__ wf, float* __restrict__ G){
  int b = blockIdx.x >> 5, pt = blockIdx.x & 31;
  int px = threadIdx.x & 127, half = threadIdx.x >> 7;
  int l = pt*128 + px;
  const size_t cb = (size_t)b*128*NL + (size_t)half*64*NL + l;
  const float* yp = y + cb;
  float loc[64]; float s=0.f, q=0.f;
  #pragma unroll
  for (int i=0;i<64;i++){ float v = yp[(size_t)i*NL]; loc[i]=v; s+=v; q+=v*v; }
  __shared__ float sh[2][2][128];
  sh[half][0][px]=s; sh[half][1][px]=q;
  __syncthreads();
  s += sh[1-half][0][px]; q += sh[1-half][1][px];
  float m = s*(1.f/128.f), rs = rsqrtf(q*(1.f/128.f)-m*m+1e-5f);
  const float* zp = z + cb;
  float* gp = G + cb;
  #pragma unroll
  for (int i=0;i<64;i++){
    int dd = half*64+i;
    float t = (loc[i]-m)*rs*wf[WF_ONW+dd] + wf[WF_ONB+dd];
    float zv = zp[(size_t)i*NL];
    gp[(size_t)i*NL] = t * (zv/(1.f+__expf(-zv)));
  }
}

// ---------------- K11A: yc = W_comb(64x128) @ G + cf_b, + per-(b,c,pt) partial stats ----------------
__global__ __launch_bounds__(256) void k11A_proj(const float* __restrict__ G, const float* __restrict__ wf,
                                                 const float* __restrict__ wcomb,
                                                 float* __restrict__ yc, float* __restrict__ part){
  int g = blockIdx.x >> 7, tile = blockIdx.x & 127;
  int b = tile >> 4, pt = tile & 15;
  int l = pt*256 + threadIdx.x;
  const float* gp = G + (size_t)b*128*NL + l;
  const float* W  = wcomb + g*16*128;
  float acc[16];
  #pragma unroll
  for (int c=0;c<16;c++) acc[c] = wf[WF_CFB + g*16 + c];
  for (int kk=0;kk<128;kk++){
    float v = gp[(size_t)kk*NL];
    #pragma unroll
    for (int c=0;c<16;c++) acc[c] += W[c*128+kk]*v;
  }
  float* op = yc + (size_t)b*64*NL + (size_t)g*16*NL + l;
  #pragma unroll
  for (int c=0;c<16;c++) op[(size_t)c*NL] = acc[c];
  __shared__ float redS[16][4], redQ[16][4];
  int wid = threadIdx.x>>6, lane = threadIdx.x&63;
  #pragma unroll
  for (int c=0;c<16;c++){
    float sv = acc[c], qv = acc[c]*acc[c];
    #pragma unroll
    for (int o=32;o>0;o>>=1){ sv += __shfl_down(sv,o); qv += __shfl_down(qv,o); }
    if (!lane){ redS[c][wid]=sv; redQ[c][wid]=qv; }
  }
  __syncthreads();
  if (threadIdx.x < 16){
    int c = threadIdx.x;
    float sv = redS[c][0]+redS[c][1]+redS[c][2]+redS[c][3];
    float qv = redQ[c][0]+redQ[c][1]+redQ[c][2]+redQ[c][3];
    int cc = g*16 + c;
    size_t pidx = (((size_t)b*64 + cc)*16 + pt)*2;
    part[pidx] = sv; part[pidx+1] = qv;
  }
}

// ---------------- K11b: finalize per-(b,c) mean/rsqrt ----------------
__global__ __launch_bounds__(256) void k11b_stats(const float* __restrict__ part, float* __restrict__ stats){
  int i = blockIdx.x*256 + threadIdx.x;
  if (i >= 512) return;
  float s=0.f, q=0.f;
  #pragma unroll
  for (int t2=0;t2<16;t2++){ s += part[((size_t)i*16+t2)*2]; q += part[((size_t)i*16+t2)*2+1]; }
  float m = s*(1.f/NL), va = q*(1.f/NL) - m*m;
  stats[i*2] = m; stats[i*2+1] = rsqrtf(va+1e-5f);
}

// ---------------- K11c: out = x1 + inorm(yc), write f32 ----------------
__global__ __launch_bounds__(256) void k11c_final(const float* __restrict__ yc, const float* __restrict__ stats,
                                                  const float* __restrict__ x1, float* __restrict__ out){
  int bc = blockIdx.x;
  float m = stats[bc*2], rs = stats[bc*2+1];
  size_t base = (size_t)bc*NL;
  for (int i=threadIdx.x;i<NL;i+=256){
    float v = (yc[base+i]-m)*rs;
    out[base+i] = x1[base+i] + v;
  }
}

// ---------------- host ----------------
extern "C" void kernel_launch(void* const* d_in, const int* in_sizes, int n_in,
                              void* d_out, int out_size, void* d_ws, size_t ws_size,
                              hipStream_t stream) {
  if (ws_size < WS_NEED_FLOATS * sizeof(float)) return;  // insufficient scratch; bail cleanly
  const float* x     = (const float*)d_in[0];
  const float* dw3w  = (const float*)d_in[1];
  const float* dw3b  = (const float*)d_in[2];
  const float* dw5w  = (const float*)d_in[3];
  const float* dw5b  = (const float*)d_in[4];
  const float* dw7w  = (const float*)d_in[5];
  const float* dw7b  = (const float*)d_in[6];
  const float* fusew = (const float*)d_in[7];
  const float* fuseb = (const float*)d_in[8];
  const float* inpjw = (const float*)d_in[9];
  const float* c2w   = (const float*)d_in[10];
  const float* c2b   = (const float*)d_in[11];
  const float* xpw   = (const float*)d_in[12];
  const float* dtw   = (const float*)d_in[13];
  const float* dtb   = (const float*)d_in[14];
  const float* alog  = (const float*)d_in[15];
  const float* dpv   = (const float*)d_in[16];
  const float* onw   = (const float*)d_in[17];
  const float* onb   = (const float*)d_in[18];
  const float* opw   = (const float*)d_in[19];
  const float* cfw   = (const float*)d_in[20];
  const float* cfb   = (const float*)d_in[21];

  float* ws    = (float*)d_ws;
  float* wf    = ws + OFF_WF;
  float* wcomb = ws + OFF_WCOMB;
  float* feats = ws + OFF_FEATS;
  float* nstat = ws + OFF_NSTAT;
  float* xf    = ws + OFF_XF;
  float* x1    = ws + OFF_X1;
  float* xmraw = ws + OFF_XMRAW;
  float* z     = ws + OFF_Z;
  float* xmc   = ws + OFF_XMC;
  float* Bmw   = ws + OFF_BMAT;
  float* Cmw   = ws + OFF_CMAT;
  float* delta = ws + OFF_DELTA;
  float* Acb   = ws + OFF_AC;
  float* Bcb   = ws + OFF_BC;
  float* Hi    = ws + OFF_HINIT;
  float* yscan = ws + OFF_YSCAN;
  float* G     = ws + OFF_G;
  float* yc    = ws + OFF_YC;
  float* part  = ws + OFF_PART;
  float* stats = ws + OFF_STATS;

  CvtArgs ca; int ns = 0;
  auto add = [&](const float* s, int off, int n, int op){
    ca.d[ns].src = s; ca.d[ns].dst = wf + off; ca.d[ns].n = n; ca.d[ns].op = op; ns++;
  };
  add(dw3w, WF_DW3, 576, 0);   add(dw5w, WF_DW5, 1600, 0);  add(dw7w, WF_DW7, 3136, 0);
  add(dw3b, WF_B3, 64, 0);     add(dw5b, WF_B5, 64, 0);     add(dw7b, WF_B7, 64, 0);
  add(fusew, WF_FUSE, 12288, 0); add(fuseb, WF_FUSEB, 64, 0);
  add(c2w, WF_C2W, 1152, 0);   add(c2b, WF_C2B, 128, 0);
  add(xpw, WF_XPW, 4608, 0);   add(dtw, WF_DTW, 512, 0);    add(dtb, WF_DTB, 128, 0);
  add(alog, WF_A, 2048, 1);    // A = -exp(A_log)
  add(dpv, WF_DP, 128, 0);
  add(onw, WF_ONW, 128, 0);    add(onb, WF_ONB, 128, 0);
  add(opw, WF_OPW, 8192, 0);
  add(cfw, WF_CFW, 4096, 0);   add(cfb, WF_CFB, 64, 0);
  add(inpjw, WF_INPJ, 16384, 0);

  k0_cvt<<<ns, 256, 0, stream>>>(ca);
  k0b_comb<<<32, 256, 0, stream>>>(cfw, opw, wcomb);
  k1_dw<<<512, 256, 0, stream>>>(x, wf, feats, nstat);
  k2_fuse<<<512, 256, 0, stream>>>(feats, nstat, wf, xf);
  k3_norm<<<512, 256, 0, stream>>>(xf, x, x1);
  k4_inproj<<<1024, 256, 0, stream>>>(x1, wf, xmraw, z);
  k5_dw3<<<1024, 256, 0, stream>>>(xmraw, wf, xmc);
  k6_xproj<<<384, 256, 0, stream>>>(xmc, wf, Bmw, Cmw, delta);
  k7_scan1<<<1024, 128, 0, stream>>>(delta, xmc, Bmw, wf, Acb, Bcb);
  k8_mid<<<64, 256, 0, stream>>>(Acb, Bcb, Hi);
  k9_scan2<<<1024, 128, 0, stream>>>(delta, xmc, Bmw, Cmw, wf, Hi, yscan);
  k10g<<<256, 256, 0, stream>>>(yscan, z, wf, G);
  k11A_proj<<<512, 256, 0, stream>>>(G, wf, wcomb, yc, part);
  k11b_stats<<<2, 256, 0, stream>>>(part, stats);
  k11c_final<<<512, 256, 0, stream>>>(yc, stats, x1, (float*)d_out);
}